// Round 3
// baseline (118.187 us; speedup 1.0000x reference)
//
#include <hip/hip_runtime.h>
#include <cmath>

#define D 128
#define BM 128   // block tile (rows and cols)
#define NSEG 8   // segments per strip-pair
#define LOG2E 1.4426950408889634

typedef __attribute__((ext_vector_type(8))) _Float16 f16x8;
typedef __attribute__((ext_vector_type(4))) float f32x4;
typedef __attribute__((ext_vector_type(2))) float f32x2;

// async global->LDS 16B copy (global_load_lds_dwordx4); LDS dst is
// wave-uniform base + lane*16 -- swizzle lives in gsrc.
// R9/R10 post-mortem: ALWAYS pass 0 for the builtin's immediate offset;
// fold offsets into the pointer.
__device__ __forceinline__ void async_cp16(const void* g, void* l) {
    __builtin_amdgcn_global_load_lds(
        (__attribute__((address_space(1))) void*)g,
        (__attribute__((address_space(3))) void*)l, 16, 0, 0);
}

// ---------------------------------------------------------------------------
// Prep: fp32 x -> fp16 (RTN) combined [x1; x2], per-row El[r] =
// -gamma*log2e*|row|^2 (log2-domain), AND zero the 64 acc slots (block 0).
// ---------------------------------------------------------------------------
__global__ __launch_bounds__(256) void prep_kernel(
    const float* __restrict__ x1, const float* __restrict__ x2,
    _Float16* __restrict__ xh, float* __restrict__ El,
    double* __restrict__ acc, float gl, int N) {
    int tid = threadIdx.x;
    if (blockIdx.x == 0 && tid < 64) acc[tid] = 0.0;
    int r = blockIdx.x * 16 + (tid >> 4);
    if (r >= 2 * N) return;
    int l = tid & 15;
    const float* row = (r < N) ? x1 + (size_t)r * D : x2 + (size_t)(r - N) * D;
    float4 v0 = ((const float4*)row)[l * 2];
    float4 v1 = ((const float4*)row)[l * 2 + 1];
    float v[8] = {v0.x, v0.y, v0.z, v0.w, v1.x, v1.y, v1.z, v1.w};
    float p = 0.f;
    _Float16 h8[8];
#pragma unroll
    for (int j = 0; j < 8; ++j) {
        p = fmaf(v[j], v[j], p);
        h8[j] = (_Float16)v[j];   // RTN-even
    }
    *(uint4*)(xh + (size_t)r * D + l * 8) = *(uint4*)h8;
#pragma unroll
    for (int off = 8; off; off >>= 1) p += __shfl_down(p, off, 16);
    if (l == 0) El[r] = gl * p;   // gl = -gamma*log2e
}

// ---------------------------------------------------------------------------
// R13 post-mortem of R12 (52.2us == old 52.4us, MfmaUtil 26%, VALUBusy 31%,
// Occ 16%): the pipeline worked but residency fell to 2 waves/SIMD -- the
// ~1.2-1.6k-cycle per-tile serial chain (lgkm stalls + MFMA phase + ~550cy
// trans-pipe epilogue) had nothing to hide under. Removed VALU work
// (VALUBusy 46->31) moved total time ZERO => latency-exposure-bound.
//
// R13: 512-thread blocks (8 waves), wave owns 64x32 of C:
//   * 16 waves/CU (4/SIMD, launch_bounds(512,4) caps VGPR at 128) --
//     restores old residency WITH the R12 pipeline.
//   * per-wave epilogue halves (34 trans insts), per-wave MFMA phase halves
//     (32 MFMAs/tile), C = 8 frags = 32 VGPR.
//   * a[4][4]=64 VGPR (64 rows x full K); ea/eb El loads moved to per-tile
//     epilogue (keeps MFMA-phase VGPR under the 128 cap).
//   * ONE setprio pair around the whole MFMA phase (per-j pairs in R12 may
//     have fenced the compiler's ds_read software pipelining).
//   * B double-buffered 2x32KiB in LDS, global_load_lds + XOR swizzle,
//     counted vmcnt(4) (4 stage insts/thread now), raw s_barrier.
// Known/accepted: SQ_LDS_BANK_CONFLICT ~2M (~6%) from async LDS writes
// landing during ds_reads -- address later if it grows.
// Tripwire: WRITE_SIZE must stay KB-scale (spill at the 128-VGPR cap).
// Signed weight: bi==bj: +1; same class off-diag: +2; cross class: -2.
// MFMA: v_mfma_f32_16x16x32_f16 (m89/m91-HW-verified layout), unchanged.
// ---------------------------------------------------------------------------
__global__ __launch_bounds__(512, 4) void mmd_mfma_kernel(
    const _Float16* __restrict__ xh, const float* __restrict__ El,
    double* __restrict__ acc, float c2l, int N) {
    __shared__ float4 smem[2][2048];  // 64 KiB: two 32 KiB B buffers

    int tid = threadIdx.x;
    int lane = tid & 63, wave = tid >> 6;      // 8 waves
    int quad = lane >> 4, l16 = lane & 15;
    int wrow = (wave & 1) * 64;                // 2 row-groups of 64
    int wcol = (wave >> 1) * 32;               // 4 col-groups of 32

    int nt2 = 2 * N / BM;        // 128 combined block-rows
    int half = N / BM;           // first `half` are x1
    int p = blockIdx.x >> 3;     // strip pair: rows p and nt2-1-p
    int s = blockIdx.x & (NSEG - 1);
    int tpp = nt2 + 1;           // tiles per pair (129)
    int q = tpp / NSEG, r = tpp % NSEG;
    int t0 = s * q + (s < r ? s : r);
    int nt = q + (s < r ? 1 : 0);    // 16 or 17 tiles, nt >= 2 always

    // staging geometry: 4 slots/thread (32KB / 512thr / 16B), row = slot>>4,
    // granule XOR-swizzled by row&7 (granule bit3 unswizzled: bank-neutral).
    int goff[4];
#pragma unroll
    for (int i = 0; i < 4; ++i) {
        int slot = i * 512 + tid;
        int row = slot >> 4;
        int g = (slot & 15) ^ (row & 7);
        goff[i] = row * D + g * 8;
    }

    auto stage = [&](int bBase, int buf) {
        const _Float16* src = xh + (size_t)bBase * D;
#pragma unroll
        for (int i = 0; i < 4; ++i)
            async_cp16(src + goff[i], &smem[buf][i * 512 + tid]);
    };
    auto BI = [&](int tt) { return tt <= p ? p : nt2 - 1 - p; };
    auto BJ = [&](int tt) { return tt <= p ? tt : tt - p - 1; };

    // prologue: fill both buffers (tiles t0, t0+1)
    stage(BJ(t0) * BM, 0);
    stage(BJ(t0 + 1) * BM, 1);

    f16x8 a[4][4];       // A fragments: rows wrow..+64, full K=128 (64 VGPR)
    int curA = -1;
    double dsum = 0.0;

    for (int i = 0; i < nt; ++i) {
        int tt = t0 + i;
        int bi = BI(tt), bj = BJ(tt);
        int aBase = bi * BM, bBase = bj * BM;
        float w = (bi == bj) ? 1.0f : 2.0f;
        if ((bi < half) != (bj < half)) w = -2.0f;
        int cur = i & 1;

        // counted wait. Steady state: previous epilogue's El-use already
        // drained everything except stage(t+1) (4 insts) -> no-op. Iters
        // 0/1: waits exactly the prologue stage for THIS buffer. NEVER
        // vmcnt(0) mid-loop.
        if (i + 1 < nt) {
            asm volatile("s_waitcnt vmcnt(4)" ::: "memory");
        } else {
            asm volatile("s_waitcnt vmcnt(0)" ::: "memory");
        }
        __builtin_amdgcn_s_barrier();
        __builtin_amdgcn_sched_barrier(0);

        // A reload only when the strip row changes (<= 2x per block).
        if (aBase != curA) {
            curA = aBase;
#pragma unroll
            for (int u = 0; u < 4; ++u) {
                int ar = aBase + wrow + u * 16 + l16;
#pragma unroll
                for (int j = 0; j < 4; ++j) {
                    int g = (j >> 1) * 8 + (j & 1) * 4 + quad;
                    a[u][j] = *(const f16x8*)(xh + (size_t)ar * D + g * 8);
                }
            }
        }

        f32x4 C[4][2];
#pragma unroll
        for (int ti = 0; ti < 4; ++ti)
#pragma unroll
            for (int tj = 0; tj < 2; ++tj) C[ti][tj] = {0.f, 0.f, 0.f, 0.f};

        __builtin_amdgcn_s_setprio(1);
#pragma unroll
        for (int j = 0; j < 4; ++j) {
            int gb = (j >> 1) * 8 + (j & 1) * 4 + quad;
            f16x8 b[2];
#pragma unroll
            for (int u = 0; u < 2; ++u) {
                int br = wcol + u * 16 + l16;
                b[u] = *(const f16x8*)&smem[cur][br * 16 + (gb ^ (br & 7))];
            }
#pragma unroll
            for (int ti = 0; ti < 4; ++ti)
#pragma unroll
                for (int tj = 0; tj < 2; ++tj)
                    C[ti][tj] = __builtin_amdgcn_mfma_f32_16x16x32_f16(
                        a[ti][j], b[tj], C[ti][tj], 0, 0, 0);
        }
        __builtin_amdgcn_s_setprio(0);

        // epilogue: entry = exp2(c2l*d + ea) * 2^eb; accumulate in f64 regs.
        // C/D layout (m89-verified): col = lane&15, row = quad*4 + reg.
        // El loads per-tile (L1/L2-hit) -- keeps MFMA-phase VGPR < 128 cap.
        int arow0 = aBase + wrow + quad * 4;
        float4 ea4[4];
#pragma unroll
        for (int ti = 0; ti < 4; ++ti)
            ea4[ti] = *(const float4*)&El[arow0 + ti * 16];
        int bcol0 = bBase + wcol + l16;
        float ebv[2];
#pragma unroll
        for (int tj = 0; tj < 2; ++tj) ebv[tj] = El[bcol0 + tj * 16];

        f32x2 cc = {c2l, c2l};
        float lsum = 0.f;
#pragma unroll
        for (int tj = 0; tj < 2; ++tj) {
            f32x2 p2 = {0.f, 0.f};
#pragma unroll
            for (int ti = 0; ti < 4; ++ti) {
                f32x4 d = C[ti][tj];
                f32x2 a01 = cc * f32x2{d.x, d.y} + f32x2{ea4[ti].x, ea4[ti].y};
                f32x2 a23 = cc * f32x2{d.z, d.w} + f32x2{ea4[ti].z, ea4[ti].w};
                f32x2 e, e2;
                e.x = __builtin_amdgcn_exp2f(a01.x);
                e.y = __builtin_amdgcn_exp2f(a01.y);
                e2.x = __builtin_amdgcn_exp2f(a23.x);
                e2.y = __builtin_amdgcn_exp2f(a23.y);
                p2 += e + e2;
            }
            lsum = fmaf(p2.x + p2.y, __builtin_amdgcn_exp2f(ebv[tj]), lsum);
        }
        dsum += (double)lsum * (double)w;

        // all waves done reading buf[cur] -> safe to overwrite with tile t+2
        __builtin_amdgcn_sched_barrier(0);
        __builtin_amdgcn_s_barrier();
        __builtin_amdgcn_sched_barrier(0);
        if (i + 2 < nt) stage(BJ(tt + 2) * BM, cur);
    }

    // block reduction (once per block; last loop barrier ordered all LDS
    // frag reads before this reuse of the tile buffer as scratch)
#pragma unroll
    for (int off = 32; off; off >>= 1) dsum += __shfl_down(dsum, off);
    double* red = (double*)&smem[0][0];
    if (lane == 0) red[wave] = dsum;
    __syncthreads();
    if (tid == 0) {
        double t8 = 0.0;
#pragma unroll
        for (int wv = 0; wv < 8; ++wv) t8 += red[wv];
        atomicAdd(&acc[blockIdx.x & 63], t8);
    }
}

// ---------------------------------------------------------------------------
// Finalize: out = sqrt(max(S/N^2, 0)), S already = S11 + S22 - 2*S12.
// ---------------------------------------------------------------------------
__global__ __launch_bounds__(64) void mmd_finalize_kernel(
    const double* __restrict__ acc, float* __restrict__ out, int N) {
    int l = threadIdx.x;
    double v = acc[l];
#pragma unroll
    for (int off = 32; off; off >>= 1) v += __shfl_down(v, off);
    if (l == 0) {
        double nn = (double)N * (double)N;
        double s = v / nn;
        out[0] = (float)sqrt(s > 0.0 ? s : 0.0);
    }
}

extern "C" void kernel_launch(void* const* d_in, const int* in_sizes, int n_in,
                              void* d_out, int out_size, void* d_ws, size_t ws_size,
                              hipStream_t stream) {
    const float* x1 = (const float*)d_in[0];
    const float* x2 = (const float*)d_in[1];
    int N = in_sizes[0] / D;  // 8192

    // ws layout: [0,512) acc (64 doubles); El @8192 (2N f32);
    // xh @73728 (2N*128 fp16 = 4 MB). Total ~4.07 MB.
    double* acc = (double*)d_ws;
    float* El = (float*)((char*)d_ws + 8192);
    _Float16* xh = (_Float16*)((char*)d_ws + 73728);

    double lg = lgamma(0.5 * (D + 1)) - lgamma(0.5 * D);
    double gz = 2.0 * exp(lg);
    double gamma = 1.0 / (2.0 * gz * gz);
    float gl = (float)(-gamma * LOG2E);        // El scale
    float c2l = (float)(2.0 * gamma * LOG2E);  // dot scale (log2 domain)

    prep_kernel<<<(2 * N + 15) / 16, 256, 0, stream>>>(x1, x2, xh, El, acc, gl, N);

    int nt2 = 2 * N / BM;                 // 128
    int nblocks = (nt2 / 2) * NSEG;       // 64 pairs x 8 segments = 512
    mmd_mfma_kernel<<<nblocks, 512, 0, stream>>>(xh, El, acc, c2l, N);

    mmd_finalize_kernel<<<1, 64, 0, stream>>>(acc, (float*)d_out, N);
}

// Round 4
// 106.753 us; speedup vs baseline: 1.1071x; 1.1071x over previous
//
#include <hip/hip_runtime.h>
#include <cmath>

#define D 128
#define BM 128   // A rows per block tile (held in registers)
#define BN 64    // B cols per staged half-tile (LDS)
#define NSEG 12  // segments per strip-pair -> 64*12 = 768 blocks = 3/CU exactly
#define LOG2E 1.4426950408889634

typedef __attribute__((ext_vector_type(8))) _Float16 f16x8;
typedef __attribute__((ext_vector_type(4))) float f32x4;
typedef __attribute__((ext_vector_type(2))) float f32x2;

// async global->LDS 16B copy (global_load_lds_dwordx4); LDS dst is
// wave-uniform base + lane*16 -- swizzle lives in gsrc.
// R9/R10: ALWAYS pass 0 for the builtin immediate; fold offsets into ptr.
__device__ __forceinline__ void async_cp16(const void* g, void* l) {
    __builtin_amdgcn_global_load_lds(
        (__attribute__((address_space(1))) void*)g,
        (__attribute__((address_space(3))) void*)l, 16, 0, 0);
}

// ---------------------------------------------------------------------------
// Prep: fp32 x -> fp16 (RTN) combined [x1; x2], per-row El[r] =
// -gamma*log2e*|row|^2 (log2-domain), AND zero the 64 acc slots (block 0).
// ---------------------------------------------------------------------------
__global__ __launch_bounds__(256) void prep_kernel(
    const float* __restrict__ x1, const float* __restrict__ x2,
    _Float16* __restrict__ xh, float* __restrict__ El,
    double* __restrict__ acc, float gl, int N) {
    int tid = threadIdx.x;
    if (blockIdx.x == 0 && tid < 64) acc[tid] = 0.0;
    int r = blockIdx.x * 16 + (tid >> 4);
    if (r >= 2 * N) return;
    int l = tid & 15;
    const float* row = (r < N) ? x1 + (size_t)r * D : x2 + (size_t)(r - N) * D;
    float4 v0 = ((const float4*)row)[l * 2];
    float4 v1 = ((const float4*)row)[l * 2 + 1];
    float v[8] = {v0.x, v0.y, v0.z, v0.w, v1.x, v1.y, v1.z, v1.w};
    float p = 0.f;
    _Float16 h8[8];
#pragma unroll
    for (int j = 0; j < 8; ++j) {
        p = fmaf(v[j], v[j], p);
        h8[j] = (_Float16)v[j];   // RTN-even
    }
    *(uint4*)(xh + (size_t)r * D + l * 8) = *(uint4*)h8;
#pragma unroll
    for (int off = 8; off; off >>= 1) p += __shfl_down(p, off, 16);
    if (l == 0) El[r] = gl * p;   // gl = -gamma*log2e
}

// ---------------------------------------------------------------------------
// R14. Post-mortems:
//   R12 (2 waves/SIMD, pipelined): 52.2us == R0's 52.4 -- pipeline gain
//     exactly cancelled by residency loss. Latency-exposure-bound.
//   R13 (512thr, launch_bounds(512,4)): SPILLED -- gfx950 unified VGPR/AGPR
//     file means the (512,4) cap is 128 TOTAL regs < a(64)+C(32)+misc.
//     VGPR_Count fell to 64, WRITE_SIZE 16B->8.2MB, 63us. ALSO the 512-block
//     grid itself capped residency at 2 blocks/CU -- grid-limited.
// R14 delivers 3 waves/SIMD with no spill:
//   * BN=64 half-tiles: block = 128 rows (A in regs) x 64 cols (B in LDS).
//     LDS = 2 x 16 KiB double buffer = 32 KiB/block.
//   * 256 threads (4 waves), wave owns 64x32 of C: a[4][4]=64 VGPR,
//     C[4][2]=32 AGPR, total ~148 <= 170 cap at launch_bounds(256,3).
//   * NSEG=12 -> 768 blocks = exactly 3 blocks/CU = 3 waves/SIMD (+50% vs
//     R12); LDS 3x32=96 KiB/CU fits.
//   * counted s_waitcnt vmcnt(4) (4 stage insts), raw s_barrier, 2-deep
//     half-tile prefetch. NEVER vmcnt(0) mid-loop.
//   * ebv El loads pinned (sched_barrier) right after the top barrier so
//     their L2 latency hides under the MFMA phase, not the epilogue.
// Known/accepted: SQ_LDS_BANK_CONFLICT ~2.1M (deterministic, staging DMA
// writes; ~1us total). Tripwires: WRITE_SIZE KB-scale; VGPR_Count ~140-160.
// Signed weight: bi==bj: +1; same class off-diag: +2; cross class: -2.
// MFMA: v_mfma_f32_16x16x32_f16 (m89/m91-HW-verified C/D layout).
// ---------------------------------------------------------------------------
__global__ __launch_bounds__(256, 3) void mmd_mfma_kernel(
    const _Float16* __restrict__ xh, const float* __restrict__ El,
    double* __restrict__ acc, float c2l, int N) {
    __shared__ float4 smem[2][1024];  // 32 KiB: two 16 KiB B half-buffers

    int tid = threadIdx.x;
    int lane = tid & 63, wave = tid >> 6;      // 4 waves
    int quad = lane >> 4, l16 = lane & 15;
    int wrow = (wave & 1) * 64;                // 2 row-groups of 64
    int wcol = (wave >> 1) * 32;               // 2 col-groups of 32

    int nt2 = 2 * N / BM;        // 128 combined block-rows
    int half = N / BM;           // first `half` are x1
    int p = blockIdx.x / NSEG;   // strip pair: rows p and nt2-1-p
    int s = blockIdx.x % NSEG;
    int tpp = nt2 + 1;           // tiles per pair (129)
    int q = tpp / NSEG, r = tpp % NSEG;
    int t0 = s * q + (s < r ? s : r);
    int nt = q + (s < r ? 1 : 0);    // 10 or 11 tiles
    int H = 2 * nt;                  // half-tiles (BN=64 cols each)

    // staging geometry: 16 KiB / 256 thr / 16 B = 4 slots/thread.
    // row = slot>>4 (64 rows x 16 granules), granule XOR-swizzled by row&7.
    int goff[4];
#pragma unroll
    for (int i = 0; i < 4; ++i) {
        int slot = i * 256 + tid;
        int row = slot >> 4;
        int g = (slot & 15) ^ (row & 7);
        goff[i] = row * D + g * 8;
    }

    auto stage = [&](int b2Base, int buf) {
        const _Float16* src = xh + (size_t)b2Base * D;
#pragma unroll
        for (int i = 0; i < 4; ++i)
            async_cp16(src + goff[i], &smem[buf][i * 256 + tid]);
    };
    auto BI = [&](int tt) { return tt <= p ? p : nt2 - 1 - p; };
    auto BJ = [&](int tt) { return tt <= p ? tt : tt - p - 1; };

    // prologue: halves 0 and 1 of tile t0
    stage(BJ(t0) * BM, 0);
    stage(BJ(t0) * BM + BN, 1);

    f16x8 a[4][4];       // A fragments: rows wrow..+64, full K=128 (64 VGPR)
    float4 ea4[4];       // A-side El (reloaded only on strip-row change)
    int curA = -1;
    double dsum = 0.0;

    for (int ht = 0; ht < H; ++ht) {
        int tt = t0 + (ht >> 1), h = ht & 1;
        int bi = BI(tt), bj = BJ(tt);
        int aBase = bi * BM;
        int bcolBase = bj * BM + h * BN;
        float w = (bi == bj) ? 1.0f : 2.0f;
        if ((bi < half) != (bj < half)) w = -2.0f;
        int cur = ht & 1;

        // counted wait: the 4 newest outstanding loads are stage(ht+1)'s;
        // everything older (incl. stage(ht), El, A reloads) drains.
        if (ht + 1 < H) {
            asm volatile("s_waitcnt vmcnt(4)" ::: "memory");
        } else {
            asm volatile("s_waitcnt vmcnt(0)" ::: "memory");
        }
        __builtin_amdgcn_s_barrier();
        __builtin_amdgcn_sched_barrier(0);

        // B-side El for THIS half-tile: issue now, pin with sched_barrier so
        // the ~200cy L2 latency hides under the MFMA phase.
        int bcol0 = bcolBase + wcol + l16;
        float ebv0 = El[bcol0];
        float ebv1 = El[bcol0 + 16];

        // A reload only when the strip row changes (<= 2x per block).
        if (aBase != curA) {
            curA = aBase;
#pragma unroll
            for (int u = 0; u < 4; ++u) {
                int ar = aBase + wrow + u * 16 + l16;
#pragma unroll
                for (int j = 0; j < 4; ++j) {
                    int g = (j >> 1) * 8 + (j & 1) * 4 + quad;
                    a[u][j] = *(const f16x8*)(xh + (size_t)ar * D + g * 8);
                }
            }
            int arow0 = aBase + wrow + quad * 4;
#pragma unroll
            for (int ti = 0; ti < 4; ++ti)
                ea4[ti] = *(const float4*)&El[arow0 + ti * 16];
        }
        __builtin_amdgcn_sched_barrier(0);  // loads issued before MFMA phase

        f32x4 C[4][2];
#pragma unroll
        for (int ti = 0; ti < 4; ++ti)
#pragma unroll
            for (int tj = 0; tj < 2; ++tj) C[ti][tj] = {0.f, 0.f, 0.f, 0.f};

        __builtin_amdgcn_s_setprio(1);
#pragma unroll
        for (int j = 0; j < 4; ++j) {
            int gb = (j >> 1) * 8 + (j & 1) * 4 + quad;
            f16x8 b[2];
#pragma unroll
            for (int u = 0; u < 2; ++u) {
                int br = wcol + u * 16 + l16;
                b[u] = *(const f16x8*)&smem[cur][br * 16 + (gb ^ (br & 7))];
            }
#pragma unroll
            for (int ti = 0; ti < 4; ++ti)
#pragma unroll
                for (int tj = 0; tj < 2; ++tj)
                    C[ti][tj] = __builtin_amdgcn_mfma_f32_16x16x32_f16(
                        a[ti][j], b[tj], C[ti][tj], 0, 0, 0);
        }
        __builtin_amdgcn_s_setprio(0);

        // epilogue: entry = exp2(c2l*d + ea) * 2^eb; accumulate f64 in regs.
        // C/D layout (m89-verified): col = lane&15, row = quad*4 + reg.
        f32x2 cc = {c2l, c2l};
        float lsum = 0.f;
#pragma unroll
        for (int tj = 0; tj < 2; ++tj) {
            f32x2 p2 = {0.f, 0.f};
#pragma unroll
            for (int ti = 0; ti < 4; ++ti) {
                f32x4 d = C[ti][tj];
                f32x2 a01 = cc * f32x2{d.x, d.y} + f32x2{ea4[ti].x, ea4[ti].y};
                f32x2 a23 = cc * f32x2{d.z, d.w} + f32x2{ea4[ti].z, ea4[ti].w};
                f32x2 e, e2;
                e.x = __builtin_amdgcn_exp2f(a01.x);
                e.y = __builtin_amdgcn_exp2f(a01.y);
                e2.x = __builtin_amdgcn_exp2f(a23.x);
                e2.y = __builtin_amdgcn_exp2f(a23.y);
                p2 += e + e2;
            }
            lsum = fmaf(p2.x + p2.y,
                        __builtin_amdgcn_exp2f(tj ? ebv1 : ebv0), lsum);
        }
        dsum += (double)lsum * (double)w;

        // all waves done reading buf[cur] -> overwrite with half-tile ht+2
        __builtin_amdgcn_sched_barrier(0);
        __builtin_amdgcn_s_barrier();
        __builtin_amdgcn_sched_barrier(0);
        if (ht + 2 < H) {
            int tn = t0 + ((ht + 2) >> 1);     // (ht+2)&1 == h
            stage(BJ(tn) * BM + h * BN, cur);
        }
    }

    // block reduction (once per block; last bottom barrier ordered all LDS
    // frag reads before this reuse of the tile buffer as scratch)
#pragma unroll
    for (int off = 32; off; off >>= 1) dsum += __shfl_down(dsum, off);
    double* red = (double*)&smem[0][0];
    if (lane == 0) red[wave] = dsum;
    __syncthreads();
    if (tid == 0)
        atomicAdd(&acc[blockIdx.x & 63], red[0] + red[1] + red[2] + red[3]);
}

// ---------------------------------------------------------------------------
// Finalize: out = sqrt(max(S/N^2, 0)), S already = S11 + S22 - 2*S12.
// ---------------------------------------------------------------------------
__global__ __launch_bounds__(64) void mmd_finalize_kernel(
    const double* __restrict__ acc, float* __restrict__ out, int N) {
    int l = threadIdx.x;
    double v = acc[l];
#pragma unroll
    for (int off = 32; off; off >>= 1) v += __shfl_down(v, off);
    if (l == 0) {
        double nn = (double)N * (double)N;
        double s = v / nn;
        out[0] = (float)sqrt(s > 0.0 ? s : 0.0);
    }
}

extern "C" void kernel_launch(void* const* d_in, const int* in_sizes, int n_in,
                              void* d_out, int out_size, void* d_ws, size_t ws_size,
                              hipStream_t stream) {
    const float* x1 = (const float*)d_in[0];
    const float* x2 = (const float*)d_in[1];
    int N = in_sizes[0] / D;  // 8192

    // ws layout: [0,512) acc (64 doubles); El @8192 (2N f32);
    // xh @73728 (2N*128 fp16 = 4 MB). Total ~4.07 MB.
    double* acc = (double*)d_ws;
    float* El = (float*)((char*)d_ws + 8192);
    _Float16* xh = (_Float16*)((char*)d_ws + 73728);

    double lg = lgamma(0.5 * (D + 1)) - lgamma(0.5 * D);
    double gz = 2.0 * exp(lg);
    double gamma = 1.0 / (2.0 * gz * gz);
    float gl = (float)(-gamma * LOG2E);        // El scale
    float c2l = (float)(2.0 * gamma * LOG2E);  // dot scale (log2 domain)

    prep_kernel<<<(2 * N + 15) / 16, 256, 0, stream>>>(x1, x2, xh, El, acc, gl, N);

    int nblocks = 64 * NSEG;   // 64 strip-pairs x 12 segments = 768 = 3/CU
    mmd_mfma_kernel<<<nblocks, 256, 0, stream>>>(xh, El, acc, c2l, N);

    mmd_finalize_kernel<<<1, 64, 0, stream>>>(acc, (float*)d_out, N);
}